// Round 8
// baseline (3063.694 us; speedup 1.0000x reference)
//
#include <hip/hip_runtime.h>

// LSTMForecast: B=256, T=512, IN=32, H=256, OUT=1, fp32.
// Round 18: R17 transport + per-unit retry acceptance + merged 16B ring store.
//   - Ring unit = 8B {payload dword, seq dword}; a thread's two units are now
//     written by ONE aligned global_store_dwordx4 (identical byte layout
//     {p0,seq,p1,seq}; reader reads the same aligned 16B in one transaction).
//     Fixes R17's strided 8-of-16 store pattern (WRITE_SIZE was 2x model).
//   - stage_sq: per-(q,i)-unit validation; validated units are written to
//     LDS immediately and NOT re-loaded; only stragglers re-issue. Cuts
//     retry L3 read traffic ~4-8x -> less contention -> shorter RTT.
//   - Retry: no sleep first 2 attempts, then s_sleep(1). All loops bounded.
//   - Per-bg progress words (R17 race fix) retained.
//   - Protocol algebra, MFMA/gates/weights-resident structure: unchanged.

#define TT 512
#define RD 8         // ring depth (slots)
#define RETRY_LIM 4096

typedef short v8s __attribute__((ext_vector_type(8)));
typedef float v4f __attribute__((ext_vector_type(4)));
typedef unsigned v4u __attribute__((ext_vector_type(4)));
typedef unsigned short u4h __attribute__((ext_vector_type(4)));

// ws byte offsets
constexpr size_t OFF_W0    = 0;          // [sl16][g4][kc9][spl2][lane64][e8] sh = 1,179,648 B
constexpr size_t OFF_W1    = 1179648;    // [sl16][g4][kc16][spl2][lane64][e8] = 2,097,152 B
constexpr size_t OFF_BC0   = 3276800;    // fp32[1024]
constexpr size_t OFF_BC1   = 3280896;    // fp32[1024]
constexpr size_t OFF_PROG  = 3284992;    // int[8 bg][16 sl]: L1 staging progress (s+1)
constexpr size_t OFF_RING0 = 3289088;    // RD x (8 bg x 16 p x 4096 B) = 4 MB
constexpr size_t SLOT_SZ   = 8*16*4096;  // 524,288 B per slot
constexpr size_t RING_SZ   = (size_t)RD*SLOT_SZ;          // 4 MB
constexpr size_t OFF_RING1 = OFF_RING0 + RING_SZ;         // 7,483,392
// end = OFF_RING1 + RING_SZ = 11,677,696

__device__ __forceinline__ float bf2f(unsigned short h){ return __uint_as_float(((unsigned)h)<<16); }
__device__ __forceinline__ unsigned short f2bf(float f){
  unsigned u = __float_as_uint(f);
  u += 0x7FFF + ((u>>16)&1);
  return (unsigned short)(u>>16);
}
__device__ __forceinline__ float sigm(float v){ return 1.0f/(1.0f + expf(-v)); }
__device__ __forceinline__ float tanh_(float v){
  float a = fabsf(v);
  float e = expf(-2.0f*a);
  float r = (1.0f - e)/(1.0f + e);
  return copysignf(r, v);
}

// device-coherent (L1/L2-bypass) ring ops
__device__ __forceinline__ v4u ld_rg(const void* p){
  v4u r;
  asm volatile("global_load_dwordx4 %0, %1, off sc0 sc1" : "=v"(r) : "v"(p));
  return r;
}
__device__ __forceinline__ void st_u16(void* p, v4u v){
  asm volatile("global_store_dwordx4 %0, %1, off sc0 sc1" :: "v"(p), "v"(v) : "memory");
}

// back-pressure: min over MY BG's 16 prog words >= need (wave-uniform, bounded)
__device__ __forceinline__ int poll_prog(const int* base, int lane, int need, int kn){
  if (kn >= need) return kn;
  int v = 0;
  for (int it = 0; it < RETRY_LIM; ++it){
    v = __hip_atomic_load(base + (lane & 15), __ATOMIC_RELAXED, __HIP_MEMORY_SCOPE_AGENT);
    v = min(v, __shfl_xor(v, 1, 64));
    v = min(v, __shfl_xor(v, 2, 64));
    v = min(v, __shfl_xor(v, 4, 64));
    v = min(v, __shfl_xor(v, 8, 64));
    if (v >= need) return v;
    __builtin_amdgcn_s_sleep(2);
  }
  return need;   // bounded give-up: fast wrong answer, never a timeout
}

// stage NP(<=4) producers' slices with PER-UNIT acceptance:
// each (q,i) unit (32B: two 16B {pay,seq,pay,seq} quads) validates
// independently; validated -> LDS immediately; only stragglers re-load.
template<int SSTR, int HSTR, int NP>
__device__ __forceinline__ void stage_sq(const char* __restrict__ ringb, size_t bgslot,
                                         int pbase, int lane, short* Afr, int cadd, int want){
  const int seg = lane >> 5;
  const int l2  = lane & 31;
  const unsigned w = (unsigned)want;
  v4u a[NP][2], b[NP][2];
  #pragma unroll
  for (int q = 0; q < NP; ++q)
    #pragma unroll
    for (int i = 0; i < 2; ++i){
      int lq = (i*2 + seg)*64 + l2*2;
      const char* p8 = ringb + bgslot + (size_t)(pbase+q)*4096 + (size_t)lq*16;
      a[q][i] = ld_rg(p8);
      b[q][i] = ld_rg(p8 + 16);
    }
  unsigned rem = (1u << (NP*2)) - 1;          // per-lane pending (q,i) bits
  for (int it = 0; it < RETRY_LIM; ++it){
    asm volatile("s_waitcnt vmcnt(0)" ::: "memory");
    #pragma unroll
    for (int q = 0; q < NP; ++q)
      #pragma unroll
      for (int i = 0; i < 2; ++i){
        asm volatile("" : "+v"(a[q][i]), "+v"(b[q][i]));
        const unsigned bit = 1u << (q*2+i);
        if (rem & bit){
          if (a[q][i].y == w && a[q][i].w == w && b[q][i].y == w && b[q][i].w == w){
            const int p = pbase + q;
            const int sh = i*2 + seg;
            v4u wv4; wv4.x = a[q][i].x; wv4.y = a[q][i].z; wv4.z = b[q][i].x; wv4.w = b[q][i].z;
            *(v4u*)(Afr + (sh>>1)*SSTR + (sh&1)*HSTR
                    + ((p>>1)+cadd)*512 + ((p&1)*64 + l2*2)*4) = wv4;
            rem &= ~bit;
          }
        }
      }
    if (__all(rem == 0)) break;
    if (it >= 2) __builtin_amdgcn_s_sleep(1);
    #pragma unroll
    for (int q = 0; q < NP; ++q)
      #pragma unroll
      for (int i = 0; i < 2; ++i){
        if (rem & (1u << (q*2+i))){
          int lq = (i*2 + seg)*64 + l2*2;
          const char* p8 = ringb + bgslot + (size_t)(pbase+q)*4096 + (size_t)lq*16;
          a[q][i] = ld_rg(p8);
          b[q][i] = ld_rg(p8 + 16);
        }
      }
  }
}

// ---------------- pack kernel ----------------
__global__ void pack_all(const float* __restrict__ Wih0, const float* __restrict__ Whh0,
                         const float* __restrict__ bih0, const float* __restrict__ bhh0,
                         const float* __restrict__ Wih1, const float* __restrict__ Whh1,
                         const float* __restrict__ bih1, const float* __restrict__ bhh1,
                         char* __restrict__ ws, float* __restrict__ out){
  int idx = blockIdx.x*256 + threadIdx.x;
  if (idx < 589824){    // W0: [sl][g][kc9][spl][lane][e]
    int e = idx&7, lane = (idx>>3)&63, spl = (idx>>9)&1, r = idx>>10;
    int kc = r%9, r2 = r/9;
    int g = r2&3, sl = r2>>2;
    int row = g*256 + sl*16 + (lane&15);
    int k = kc*32 + (lane>>4)*8 + e;
    float w = (k < 32) ? Wih0[row*32 + k] : Whh0[row*256 + (k-32)];
    unsigned short hi = f2bf(w);
    ((unsigned short*)(ws + OFF_W0))[idx] = spl ? f2bf(w - bf2f(hi)) : hi;
    return;
  }
  idx -= 589824;
  if (idx < 1048576){   // W1: [sl][g][kc16][spl][lane][e]
    int e = idx&7, lane = (idx>>3)&63, spl = (idx>>9)&1, r = idx>>10;
    int kc = r&15, r2 = r>>4;
    int g = r2&3, sl = r2>>2;
    int row = g*256 + sl*16 + (lane&15);
    int k = kc*32 + (lane>>4)*8 + e;
    float w = (k < 256) ? Wih1[row*256 + k] : Whh1[row*256 + (k-256)];
    unsigned short hi = f2bf(w);
    ((unsigned short*)(ws + OFF_W1))[idx] = spl ? f2bf(w - bf2f(hi)) : hi;
    return;
  }
  idx -= 1048576;
  if (idx < 2048){      // combined biases [g*256+j]
    float* bc = (float*)(ws + (idx < 1024 ? OFF_BC0 : OFF_BC1));
    int j = idx & 1023;
    bc[j] = (idx < 1024) ? (bih0[j]+bhh0[j]) : (bih1[j]+bhh1[j]);
    return;
  }
  idx -= 2048;
  if (idx < 2097152){   // zero BOTH rings (8 MB contiguous from OFF_RING0)
    ((int*)(ws + OFF_RING0))[idx] = 0;
    return;
  }
  idx -= 2097152;
  if (idx < 256){ out[idx] = 0.f; return; }
  idx -= 256;
  if (idx < 128){ ((int*)(ws + OFF_PROG))[idx] = 0; return; }
}

// ---------------- persistent layer worker ----------------
template<int LAYER>
__device__ void run_layer(const float* __restrict__ x, char* __restrict__ ws,
                          const float* __restrict__ Wfc, const float* __restrict__ bfc,
                          float* __restrict__ out, int bg, int sl,
                          short* Afr, float* gatesL, float* cst, unsigned short* hbuf){
  constexpr int NKC  = LAYER ? 16 : 9;       // K chunks per split half
  constexpr int HSTR = NKC*512;              // half stride (shorts)
  constexpr int SSTR = 2*HSTR;               // spl stride
  constexpr int NFR  = 2*NKC;                // B frags per wave

  int* progp = (int*)(ws + OFF_PROG) + bg*16;   // MY BG's 16 progress words
  const char* ring0b = (const char*)(ws + OFF_RING0);
  const char* ring1b = (const char*)(ws + OFF_RING1);
  char* ringwb = (char*)(ws + (LAYER ? OFF_RING1 : OFF_RING0));

  const int tid  = threadIdx.x;
  const int lane = tid & 63;
  const int wv   = tid >> 6;       // wave == gate (i,f,g,o)
  const int m    = lane & 15;
  const int quad = lane >> 4;

  // ---- persistent B-fragments (unified VGPR/AGPR file) ----
  const unsigned short* wp = (const unsigned short*)(ws + (LAYER ? OFF_W1 : OFF_W0))
                             + (size_t)(sl*4 + wv)*NFR*512 + lane*8;
  v8s bfr[NFR];
  #pragma unroll
  for (int f = 0; f < NFR; ++f){
    v8s tmp = *(const v8s*)(wp + f*512);
    asm volatile("" : "+v"(tmp));            // anti-remat
    bfr[f] = tmp;
  }

  // ---- gate-phase constants: thread (bb, jp) owns (b=bb, j = sl*16 + jp*2 + p) ----
  const int bb = tid & 31, jp = tid >> 5;
  const float* bcp = (const float*)(ws + (LAYER ? OFF_BC1 : OFF_BC0));
  float bia[2][4];
  #pragma unroll
  for (int p = 0; p < 2; ++p)
    #pragma unroll
    for (int gg = 0; gg < 4; ++gg) bia[p][gg] = bcp[gg*256 + sl*16 + jp*2 + p];
  float wfcv[2] = {0.f, 0.f};
  if (LAYER == 1){ wfcv[0] = Wfc[sl*16 + jp*2]; wfcv[1] = Wfc[sl*16 + jp*2 + 1]; }
  float fcp = 0.f;

  const int half_b  = bb >> 4;
  const int laneloc = ((jp*2) >> 3)*16 + (bb & 15);
  const int e0h     = ((jp*2) & 7) >> 1;

  for (int i = tid; i < 544; i += 256) cst[i] = 0.f;
  __syncthreads();

  const int xb = tid >> 3, xs = tid & 7;     // x staging role (L0)
  int kn_bp = 0;                             // cached back-pressure minimum

  for (int t = 0; t < TT; ++t){
    size_t bgslot_prev = (size_t)((t+RD-1)&(RD-1))*SLOT_SZ + (size_t)bg*65536;
    size_t bgslot_cur  = (size_t)(t&(RD-1))*SLOT_SZ + (size_t)bg*65536;

    if (LAYER == 0){
      float4 xv = *(const float4*)(x + ((size_t)(bg*32 + xb)*TT + t)*32 + xs*4);
      // back-pressure: MY BG's L1 must have staged ring0 step t-RD first
      if (wv == 0 && t >= RD) kn_bp = poll_prog(progp, lane, t-RD+1, kn_bp);
      // stage my 4 producers' h0[t-1] (seq == t), per-unit accept
      stage_sq<SSTR,HSTR,4>(ring0b, bgslot_prev, wv*4, lane, Afr, 1, t);
      // x chunk (c=0) fragment writes
      {
        u4h hi4, lo4;
        hi4.x = f2bf(xv.x); lo4.x = f2bf(xv.x - bf2f(hi4.x));
        hi4.y = f2bf(xv.y); lo4.y = f2bf(xv.y - bf2f(hi4.y));
        hi4.z = f2bf(xv.z); lo4.z = f2bf(xv.z - bf2f(hi4.z));
        hi4.w = f2bf(xv.w); lo4.w = f2bf(xv.w - bf2f(hi4.w));
        int lx = (xs>>1)*16 + (xb&15), hx = xb>>4, ex = (xs&1)*4;
        *(u4h*)(Afr + 0*SSTR + hx*HSTR + lx*8 + ex) = hi4;
        *(u4h*)(Afr + 1*SSTR + hx*HSTR + lx*8 + ex) = lo4;
      }
    } else {
      // wave-split: waves 0-1 stage ring1 (h1[t-1], seq t); waves 2-3 ring0 (h0[t], seq t+1)
      if (wv < 2){
        stage_sq<SSTR,HSTR,4>(ring1b, bgslot_prev, wv*8,     lane, Afr, 8, t);
        stage_sq<SSTR,HSTR,4>(ring1b, bgslot_prev, wv*8 + 4, lane, Afr, 8, t);
      } else {
        stage_sq<SSTR,HSTR,4>(ring0b, bgslot_cur, (wv-2)*8,     lane, Afr, 0, t+1);
        stage_sq<SSTR,HSTR,4>(ring0b, bgslot_cur, (wv-2)*8 + 4, lane, Afr, 0, t+1);
      }
    }
    __syncthreads();                           // B1: Afr complete

    // L1: publish MY BG's ring0 staging progress (fire-and-forget, monotone)
    if (LAYER == 1 && tid == 0)
      __hip_atomic_store(progp + sl, t+1, __ATOMIC_RELAXED, __HIP_MEMORY_SCOPE_AGENT);

    // ---- MFMA: 3-product split, dual accumulators ----
    v4f a0a={0,0,0,0}, a0b={0,0,0,0}, a1a={0,0,0,0}, a1b={0,0,0,0};
    #pragma unroll
    for (int c = 0; c < NKC; ++c){
      v8s A0h = *(const v8s*)(Afr + 0*SSTR + 0*HSTR + c*512 + lane*8);
      v8s A1h = *(const v8s*)(Afr + 0*SSTR + 1*HSTR + c*512 + lane*8);
      v8s A0l = *(const v8s*)(Afr + 1*SSTR + 0*HSTR + c*512 + lane*8);
      v8s A1l = *(const v8s*)(Afr + 1*SSTR + 1*HSTR + c*512 + lane*8);
      v8s Bh = bfr[c*2+0], Bl = bfr[c*2+1];
      if (c & 1){
        a0b = __builtin_amdgcn_mfma_f32_16x16x32_bf16(A0h, Bh, a0b, 0,0,0);
        a0b = __builtin_amdgcn_mfma_f32_16x16x32_bf16(A0h, Bl, a0b, 0,0,0);
        a0b = __builtin_amdgcn_mfma_f32_16x16x32_bf16(A0l, Bh, a0b, 0,0,0);
        a1b = __builtin_amdgcn_mfma_f32_16x16x32_bf16(A1h, Bh, a1b, 0,0,0);
        a1b = __builtin_amdgcn_mfma_f32_16x16x32_bf16(A1h, Bl, a1b, 0,0,0);
        a1b = __builtin_amdgcn_mfma_f32_16x16x32_bf16(A1l, Bh, a1b, 0,0,0);
      } else {
        a0a = __builtin_amdgcn_mfma_f32_16x16x32_bf16(A0h, Bh, a0a, 0,0,0);
        a0a = __builtin_amdgcn_mfma_f32_16x16x32_bf16(A0h, Bl, a0a, 0,0,0);
        a0a = __builtin_amdgcn_mfma_f32_16x16x32_bf16(A0l, Bh, a0a, 0,0,0);
        a1a = __builtin_amdgcn_mfma_f32_16x16x32_bf16(A1h, Bh, a1a, 0,0,0);
        a1a = __builtin_amdgcn_mfma_f32_16x16x32_bf16(A1h, Bl, a1a, 0,0,0);
        a1a = __builtin_amdgcn_mfma_f32_16x16x32_bf16(A1l, Bh, a1a, 0,0,0);
      }
    }
    {
      v4f acc0 = a0a + a0b, acc1 = a1a + a1b;
      float* gw = gatesL + wv*544;
      #pragma unroll
      for (int r = 0; r < 4; ++r){
        gw[(quad*4 + r)*17 + m]      = acc0[r];
        gw[(16 + quad*4 + r)*17 + m] = acc1[r];
      }
    }
    __syncthreads();                           // B2: gates ready

    // ---- gate nonlinearity + state + hbuf ----
    {
      float hv[2];
      #pragma unroll
      for (int p = 0; p < 2; ++p){
        int jl = jp*2 + p;
        float gi = gatesL[0*544 + bb*17 + jl] + bia[p][0];
        float gf = gatesL[1*544 + bb*17 + jl] + bia[p][1];
        float gG = gatesL[2*544 + bb*17 + jl] + bia[p][2];
        float go = gatesL[3*544 + bb*17 + jl] + bia[p][3];
        float iv = sigm(gi), fv = sigm(gf), gv = tanh_(gG), ov = sigm(go);
        float cc = fv*cst[bb*17 + jl] + iv*gv;
        cst[bb*17 + jl] = cc;
        hv[p] = ov*tanh_(cc);
      }
      unsigned short h0h = f2bf(hv[0]), h1h = f2bf(hv[1]);
      unsigned short h0l = f2bf(hv[0] - bf2f(h0h)), h1l = f2bf(hv[1] - bf2f(h1h));
      unsigned* hb = (unsigned*)hbuf;
      hb[      half_b*128 + laneloc*4 + e0h] = (unsigned)h0h | ((unsigned)h1h << 16);
      hb[256 + half_b*128 + laneloc*4 + e0h] = (unsigned)h0l | ((unsigned)h1l << 16);
      if (LAYER == 1 && t == TT-1) fcp = hv[0]*wfcv[0] + hv[1]*wfcv[1];
    }
    __syncthreads();                           // B3: hbuf ready

    // ---- ring write: ONE aligned 16B store per thread {p0,seq,p1,seq} ----
    {
      const unsigned* hb32 = (const unsigned*)hbuf;
      const unsigned sq = (unsigned)(t+1);
      v4u u; u.x = hb32[2*tid]; u.y = sq; u.z = hb32[2*tid+1]; u.w = sq;
      char* dst = ringwb + (size_t)(t&(RD-1))*SLOT_SZ + (size_t)bg*65536
                + (size_t)sl*4096 + (size_t)tid*16;
      st_u16(dst, u);
    }
  }

  // ---- FC epilogue ----
  if (LAYER == 1){
    __syncthreads();
    gatesL[tid] = fcp;
    __syncthreads();
    if (tid < 32){
      float sm = 0.f;
      #pragma unroll
      for (int q = 0; q < 8; ++q) sm += gatesL[q*32 + tid];
      if (sl == 0) sm += bfc[0];
      atomicAdd(&out[bg*32 + tid], sm);
    }
  }
}

__global__ __launch_bounds__(256,1) void lstm_pipe(const float* __restrict__ x, char* __restrict__ ws,
                                                   const float* __restrict__ Wfc, const float* __restrict__ bfc,
                                                   float* __restrict__ out){
  __shared__ __align__(16) short Afr[32768];          // 65,536 B
  __shared__ __align__(16) float gatesL[2176];        //  8,704 B
  __shared__ __align__(16) float cst[544];            //  2,176 B
  __shared__ __align__(16) unsigned short hbuf[1024]; //  2,048 B
  const int bid = blockIdx.x;
  // bid&7 = bg (XCD round-robin friendly; correctness mapping-independent)
  const int bg = bid & 7, r = bid >> 3, layer = r >> 4, sl = r & 15;
  if (layer == 0) run_layer<0>(x, ws, Wfc, bfc, out, bg, sl, Afr, gatesL, cst, hbuf);
  else            run_layer<1>(x, ws, Wfc, bfc, out, bg, sl, Afr, gatesL, cst, hbuf);
}

extern "C" void kernel_launch(void* const* d_in, const int* in_sizes, int n_in,
                              void* d_out, int out_size, void* d_ws, size_t ws_size,
                              hipStream_t stream) {
  const float* x    = (const float*)d_in[0];
  const float* Wih0 = (const float*)d_in[1];
  const float* Whh0 = (const float*)d_in[2];
  const float* bih0 = (const float*)d_in[3];
  const float* bhh0 = (const float*)d_in[4];
  const float* Wih1 = (const float*)d_in[5];
  const float* Whh1 = (const float*)d_in[6];
  const float* bih1 = (const float*)d_in[7];
  const float* bhh1 = (const float*)d_in[8];
  const float* Wfc  = (const float*)d_in[9];
  const float* bfc  = (const float*)d_in[10];
  float* out = (float*)d_out;
  char* ws   = (char*)d_ws;
  (void)in_sizes; (void)n_in; (void)out_size; (void)ws_size;

  // pack items: 589824+1048576+2048+2097152+256+128 = 3,737,984 -> 14602 blocks
  pack_all<<<14602, 256, 0, stream>>>(Wih0, Whh0, bih0, bhh0, Wih1, Whh1, bih1, bhh1, ws, out);
  lstm_pipe<<<256, 256, 0, stream>>>(x, ws, Wfc, bfc, out);
}

// Round 9
// 2531.099 us; speedup vs baseline: 1.2104x; 1.2104x over previous
//
#include <hip/hip_runtime.h>

// LSTMForecast: B=256, T=512, IN=32, H=256, OUT=1, fp32.
// Round 19: R17 transport (proven 2640us) + merged 16B store + bp-prefetch.
//   - stage_sq: R17 verbatim (whole-set validate, s_sleep(2) pacing).
//     R18 lesson: aggressive spinning inflates fabric RTT for everyone.
//   - Ring write: ONE aligned global_store_dwordx4 {p0,seq,p1,seq}
//     (R18-verified: halves write transactions; atomicity strictly better).
//   - Back-pressure prefetch (L0, wv0): progress-word loads issued at
//     iteration start, validated after gates (RTT hidden under compute);
//     bounded fallback poll on miss. Check still gates ring write via B3.
//   - Per-bg progress words; protocol algebra unchanged from R17.

#define TT 512
#define RD 8         // ring depth (slots)
#define RETRY_LIM 4096

typedef short v8s __attribute__((ext_vector_type(8)));
typedef float v4f __attribute__((ext_vector_type(4)));
typedef unsigned v4u __attribute__((ext_vector_type(4)));
typedef unsigned short u4h __attribute__((ext_vector_type(4)));

// ws byte offsets
constexpr size_t OFF_W0    = 0;          // [sl16][g4][kc9][spl2][lane64][e8] sh = 1,179,648 B
constexpr size_t OFF_W1    = 1179648;    // [sl16][g4][kc16][spl2][lane64][e8] = 2,097,152 B
constexpr size_t OFF_BC0   = 3276800;    // fp32[1024]
constexpr size_t OFF_BC1   = 3280896;    // fp32[1024]
constexpr size_t OFF_PROG  = 3284992;    // int[8 bg][16 sl]: L1 staging progress (s+1)
constexpr size_t OFF_RING0 = 3289088;    // RD x (8 bg x 16 p x 4096 B) = 4 MB
constexpr size_t SLOT_SZ   = 8*16*4096;  // 524,288 B per slot
constexpr size_t RING_SZ   = (size_t)RD*SLOT_SZ;          // 4 MB
constexpr size_t OFF_RING1 = OFF_RING0 + RING_SZ;         // 7,483,392
// end = OFF_RING1 + RING_SZ = 11,677,696

__device__ __forceinline__ float bf2f(unsigned short h){ return __uint_as_float(((unsigned)h)<<16); }
__device__ __forceinline__ unsigned short f2bf(float f){
  unsigned u = __float_as_uint(f);
  u += 0x7FFF + ((u>>16)&1);
  return (unsigned short)(u>>16);
}
__device__ __forceinline__ float sigm(float v){ return 1.0f/(1.0f + expf(-v)); }
__device__ __forceinline__ float tanh_(float v){
  float a = fabsf(v);
  float e = expf(-2.0f*a);
  float r = (1.0f - e)/(1.0f + e);
  return copysignf(r, v);
}

// device-coherent ring ops
__device__ __forceinline__ v4u ld_rg(const void* p){
  v4u r;
  asm volatile("global_load_dwordx4 %0, %1, off sc0 sc1" : "=v"(r) : "v"(p));
  return r;
}
__device__ __forceinline__ void st_u16(void* p, v4u v){
  asm volatile("global_store_dwordx4 %0, %1, off sc0 sc1" :: "v"(p), "v"(v) : "memory");
}

// back-pressure fallback poll: min over MY BG's 16 prog words >= need (bounded)
__device__ __forceinline__ int poll_prog(const int* base, int lane, int need, int kn){
  if (kn >= need) return kn;
  int v = 0;
  for (int it = 0; it < RETRY_LIM; ++it){
    v = __hip_atomic_load(base + (lane & 15), __ATOMIC_RELAXED, __HIP_MEMORY_SCOPE_AGENT);
    v = min(v, __shfl_xor(v, 1, 64));
    v = min(v, __shfl_xor(v, 2, 64));
    v = min(v, __shfl_xor(v, 4, 64));
    v = min(v, __shfl_xor(v, 8, 64));
    if (v >= need) return v;
    __builtin_amdgcn_s_sleep(2);
  }
  return need;   // bounded give-up: fast wrong answer, never a timeout
}

// stage NP(<=4) producers' slices: speculative load + seq-validate + retry
// (R17 verbatim: whole-set validation, s_sleep(2) pacing, bounded).
template<int SSTR, int HSTR, int NP>
__device__ __forceinline__ void stage_sq(const char* __restrict__ ringb, size_t bgslot,
                                         int pbase, int lane, short* Afr, int cadd, int want){
  const int seg = lane >> 5;
  const int l2  = lane & 31;
  v4u a[NP][2], b[NP][2];
  const unsigned w = (unsigned)want;
  for (int it = 0; it < RETRY_LIM; ++it){
    #pragma unroll
    for (int q = 0; q < NP; ++q){
      #pragma unroll
      for (int i = 0; i < 2; ++i){
        int lq = (i*2 + seg)*64 + l2*2;
        const char* p8 = ringb + bgslot + (size_t)(pbase+q)*4096 + (size_t)lq*16;
        a[q][i] = ld_rg(p8);
        b[q][i] = ld_rg(p8 + 16);
      }
    }
    asm volatile("s_waitcnt vmcnt(0)" ::: "memory");
    #pragma unroll
    for (int q = 0; q < NP; ++q){
      #pragma unroll
      for (int i = 0; i < 2; ++i){
        asm volatile("" : "+v"(a[q][i]));
        asm volatile("" : "+v"(b[q][i]));
      }
    }
    int ok = 1;
    #pragma unroll
    for (int q = 0; q < NP; ++q)
      #pragma unroll
      for (int i = 0; i < 2; ++i)
        ok &= (a[q][i].y == w) & (a[q][i].w == w) & (b[q][i].y == w) & (b[q][i].w == w);
    if (__all(ok)) break;
    __builtin_amdgcn_s_sleep(2);
  }
  #pragma unroll
  for (int q = 0; q < NP; ++q){
    int p = pbase + q;
    #pragma unroll
    for (int i = 0; i < 2; ++i){
      int sh = i*2 + seg;
      v4u wv4; wv4.x = a[q][i].x; wv4.y = a[q][i].z; wv4.z = b[q][i].x; wv4.w = b[q][i].z;
      *(v4u*)(Afr + (sh>>1)*SSTR + (sh&1)*HSTR
              + ((p>>1)+cadd)*512 + ((p&1)*64 + l2*2)*4) = wv4;
    }
  }
}

// ---------------- pack kernel ----------------
__global__ void pack_all(const float* __restrict__ Wih0, const float* __restrict__ Whh0,
                         const float* __restrict__ bih0, const float* __restrict__ bhh0,
                         const float* __restrict__ Wih1, const float* __restrict__ Whh1,
                         const float* __restrict__ bih1, const float* __restrict__ bhh1,
                         char* __restrict__ ws, float* __restrict__ out){
  int idx = blockIdx.x*256 + threadIdx.x;
  if (idx < 589824){    // W0: [sl][g][kc9][spl][lane][e]
    int e = idx&7, lane = (idx>>3)&63, spl = (idx>>9)&1, r = idx>>10;
    int kc = r%9, r2 = r/9;
    int g = r2&3, sl = r2>>2;
    int row = g*256 + sl*16 + (lane&15);
    int k = kc*32 + (lane>>4)*8 + e;
    float w = (k < 32) ? Wih0[row*32 + k] : Whh0[row*256 + (k-32)];
    unsigned short hi = f2bf(w);
    ((unsigned short*)(ws + OFF_W0))[idx] = spl ? f2bf(w - bf2f(hi)) : hi;
    return;
  }
  idx -= 589824;
  if (idx < 1048576){   // W1: [sl][g][kc16][spl][lane][e]
    int e = idx&7, lane = (idx>>3)&63, spl = (idx>>9)&1, r = idx>>10;
    int kc = r&15, r2 = r>>4;
    int g = r2&3, sl = r2>>2;
    int row = g*256 + sl*16 + (lane&15);
    int k = kc*32 + (lane>>4)*8 + e;
    float w = (k < 256) ? Wih1[row*256 + k] : Whh1[row*256 + (k-256)];
    unsigned short hi = f2bf(w);
    ((unsigned short*)(ws + OFF_W1))[idx] = spl ? f2bf(w - bf2f(hi)) : hi;
    return;
  }
  idx -= 1048576;
  if (idx < 2048){      // combined biases [g*256+j]
    float* bc = (float*)(ws + (idx < 1024 ? OFF_BC0 : OFF_BC1));
    int j = idx & 1023;
    bc[j] = (idx < 1024) ? (bih0[j]+bhh0[j]) : (bih1[j]+bhh1[j]);
    return;
  }
  idx -= 2048;
  if (idx < 2097152){   // zero BOTH rings (8 MB contiguous from OFF_RING0)
    ((int*)(ws + OFF_RING0))[idx] = 0;
    return;
  }
  idx -= 2097152;
  if (idx < 256){ out[idx] = 0.f; return; }
  idx -= 256;
  if (idx < 128){ ((int*)(ws + OFF_PROG))[idx] = 0; return; }
}

// ---------------- persistent layer worker ----------------
template<int LAYER>
__device__ void run_layer(const float* __restrict__ x, char* __restrict__ ws,
                          const float* __restrict__ Wfc, const float* __restrict__ bfc,
                          float* __restrict__ out, int bg, int sl,
                          short* Afr, float* gatesL, float* cst, unsigned short* hbuf){
  constexpr int NKC  = LAYER ? 16 : 9;       // K chunks per split half
  constexpr int HSTR = NKC*512;              // half stride (shorts)
  constexpr int SSTR = 2*HSTR;               // spl stride
  constexpr int NFR  = 2*NKC;                // B frags per wave

  int* progp = (int*)(ws + OFF_PROG) + bg*16;   // MY BG's 16 progress words
  const char* ring0b = (const char*)(ws + OFF_RING0);
  const char* ring1b = (const char*)(ws + OFF_RING1);
  char* ringwb = (char*)(ws + (LAYER ? OFF_RING1 : OFF_RING0));

  const int tid  = threadIdx.x;
  const int lane = tid & 63;
  const int wv   = tid >> 6;       // wave == gate (i,f,g,o)
  const int m    = lane & 15;
  const int quad = lane >> 4;

  // ---- persistent B-fragments (unified VGPR/AGPR file) ----
  const unsigned short* wp = (const unsigned short*)(ws + (LAYER ? OFF_W1 : OFF_W0))
                             + (size_t)(sl*4 + wv)*NFR*512 + lane*8;
  v8s bfr[NFR];
  #pragma unroll
  for (int f = 0; f < NFR; ++f){
    v8s tmp = *(const v8s*)(wp + f*512);
    asm volatile("" : "+v"(tmp));            // anti-remat
    bfr[f] = tmp;
  }

  // ---- gate-phase constants: thread (bb, jp) owns (b=bb, j = sl*16 + jp*2 + p) ----
  const int bb = tid & 31, jp = tid >> 5;
  const float* bcp = (const float*)(ws + (LAYER ? OFF_BC1 : OFF_BC0));
  float bia[2][4];
  #pragma unroll
  for (int p = 0; p < 2; ++p)
    #pragma unroll
    for (int gg = 0; gg < 4; ++gg) bia[p][gg] = bcp[gg*256 + sl*16 + jp*2 + p];
  float wfcv[2] = {0.f, 0.f};
  if (LAYER == 1){ wfcv[0] = Wfc[sl*16 + jp*2]; wfcv[1] = Wfc[sl*16 + jp*2 + 1]; }
  float fcp = 0.f;

  const int half_b  = bb >> 4;
  const int laneloc = ((jp*2) >> 3)*16 + (bb & 15);
  const int e0h     = ((jp*2) & 7) >> 1;

  for (int i = tid; i < 544; i += 256) cst[i] = 0.f;
  __syncthreads();

  const int xb = tid >> 3, xs = tid & 7;     // x staging role (L0)
  int kn_bp = 0;                             // cached back-pressure minimum

  for (int t = 0; t < TT; ++t){
    size_t bgslot_prev = (size_t)((t+RD-1)&(RD-1))*SLOT_SZ + (size_t)bg*65536;
    size_t bgslot_cur  = (size_t)(t&(RD-1))*SLOT_SZ + (size_t)bg*65536;

    // back-pressure prefetch state (L0, wave 0 only; wave-uniform condition)
    int bpv = 0x7fffffff;
    const bool needbp = (LAYER == 0) && (wv == 0) && (t >= RD) && (kn_bp < t-RD+1);

    if (LAYER == 0){
      float4 xv = *(const float4*)(x + ((size_t)(bg*32 + xb)*TT + t)*32 + xs*4);
      // issue progress-word loads now; validate after gates (RTT hidden)
      if (needbp)
        asm volatile("global_load_dword %0, %1, off sc0 sc1"
                     : "=v"(bpv) : "v"(progp + (lane & 15)));
      // stage my 4 producers' h0[t-1] (seq == t), speculative+validate
      stage_sq<SSTR,HSTR,4>(ring0b, bgslot_prev, wv*4, lane, Afr, 1, t);
      // x chunk (c=0) fragment writes
      {
        u4h hi4, lo4;
        hi4.x = f2bf(xv.x); lo4.x = f2bf(xv.x - bf2f(hi4.x));
        hi4.y = f2bf(xv.y); lo4.y = f2bf(xv.y - bf2f(hi4.y));
        hi4.z = f2bf(xv.z); lo4.z = f2bf(xv.z - bf2f(hi4.z));
        hi4.w = f2bf(xv.w); lo4.w = f2bf(xv.w - bf2f(hi4.w));
        int lx = (xs>>1)*16 + (xb&15), hx = xb>>4, ex = (xs&1)*4;
        *(u4h*)(Afr + 0*SSTR + hx*HSTR + lx*8 + ex) = hi4;
        *(u4h*)(Afr + 1*SSTR + hx*HSTR + lx*8 + ex) = lo4;
      }
    } else {
      // wave-split: waves 0-1 stage ring1 (h1[t-1], seq t); waves 2-3 ring0 (h0[t], seq t+1)
      if (wv < 2){
        stage_sq<SSTR,HSTR,4>(ring1b, bgslot_prev, wv*8,     lane, Afr, 8, t);
        stage_sq<SSTR,HSTR,4>(ring1b, bgslot_prev, wv*8 + 4, lane, Afr, 8, t);
      } else {
        stage_sq<SSTR,HSTR,4>(ring0b, bgslot_cur, (wv-2)*8,     lane, Afr, 0, t+1);
        stage_sq<SSTR,HSTR,4>(ring0b, bgslot_cur, (wv-2)*8 + 4, lane, Afr, 0, t+1);
      }
    }
    __syncthreads();                           // B1: Afr complete

    // L1: publish MY BG's ring0 staging progress (fire-and-forget, monotone)
    if (LAYER == 1 && tid == 0)
      __hip_atomic_store(progp + sl, t+1, __ATOMIC_RELAXED, __HIP_MEMORY_SCOPE_AGENT);

    // ---- MFMA: 3-product split, dual accumulators ----
    v4f a0a={0,0,0,0}, a0b={0,0,0,0}, a1a={0,0,0,0}, a1b={0,0,0,0};
    #pragma unroll
    for (int c = 0; c < NKC; ++c){
      v8s A0h = *(const v8s*)(Afr + 0*SSTR + 0*HSTR + c*512 + lane*8);
      v8s A1h = *(const v8s*)(Afr + 0*SSTR + 1*HSTR + c*512 + lane*8);
      v8s A0l = *(const v8s*)(Afr + 1*SSTR + 0*HSTR + c*512 + lane*8);
      v8s A1l = *(const v8s*)(Afr + 1*SSTR + 1*HSTR + c*512 + lane*8);
      v8s Bh = bfr[c*2+0], Bl = bfr[c*2+1];
      if (c & 1){
        a0b = __builtin_amdgcn_mfma_f32_16x16x32_bf16(A0h, Bh, a0b, 0,0,0);
        a0b = __builtin_amdgcn_mfma_f32_16x16x32_bf16(A0h, Bl, a0b, 0,0,0);
        a0b = __builtin_amdgcn_mfma_f32_16x16x32_bf16(A0l, Bh, a0b, 0,0,0);
        a1b = __builtin_amdgcn_mfma_f32_16x16x32_bf16(A1h, Bh, a1b, 0,0,0);
        a1b = __builtin_amdgcn_mfma_f32_16x16x32_bf16(A1h, Bl, a1b, 0,0,0);
        a1b = __builtin_amdgcn_mfma_f32_16x16x32_bf16(A1l, Bh, a1b, 0,0,0);
      } else {
        a0a = __builtin_amdgcn_mfma_f32_16x16x32_bf16(A0h, Bh, a0a, 0,0,0);
        a0a = __builtin_amdgcn_mfma_f32_16x16x32_bf16(A0h, Bl, a0a, 0,0,0);
        a0a = __builtin_amdgcn_mfma_f32_16x16x32_bf16(A0l, Bh, a0a, 0,0,0);
        a1a = __builtin_amdgcn_mfma_f32_16x16x32_bf16(A1h, Bh, a1a, 0,0,0);
        a1a = __builtin_amdgcn_mfma_f32_16x16x32_bf16(A1h, Bl, a1a, 0,0,0);
        a1a = __builtin_amdgcn_mfma_f32_16x16x32_bf16(A1l, Bh, a1a, 0,0,0);
      }
    }
    {
      v4f acc0 = a0a + a0b, acc1 = a1a + a1b;
      float* gw = gatesL + wv*544;
      #pragma unroll
      for (int r = 0; r < 4; ++r){
        gw[(quad*4 + r)*17 + m]      = acc0[r];
        gw[(16 + quad*4 + r)*17 + m] = acc1[r];
      }
    }
    __syncthreads();                           // B2: gates ready

    // ---- gate nonlinearity + state + hbuf ----
    {
      float hv[2];
      #pragma unroll
      for (int p = 0; p < 2; ++p){
        int jl = jp*2 + p;
        float gi = gatesL[0*544 + bb*17 + jl] + bia[p][0];
        float gf = gatesL[1*544 + bb*17 + jl] + bia[p][1];
        float gG = gatesL[2*544 + bb*17 + jl] + bia[p][2];
        float go = gatesL[3*544 + bb*17 + jl] + bia[p][3];
        float iv = sigm(gi), fv = sigm(gf), gv = tanh_(gG), ov = sigm(go);
        float cc = fv*cst[bb*17 + jl] + iv*gv;
        cst[bb*17 + jl] = cc;
        hv[p] = ov*tanh_(cc);
      }
      unsigned short h0h = f2bf(hv[0]), h1h = f2bf(hv[1]);
      unsigned short h0l = f2bf(hv[0] - bf2f(h0h)), h1l = f2bf(hv[1] - bf2f(h1h));
      unsigned* hb = (unsigned*)hbuf;
      hb[      half_b*128 + laneloc*4 + e0h] = (unsigned)h0h | ((unsigned)h1h << 16);
      hb[256 + half_b*128 + laneloc*4 + e0h] = (unsigned)h0l | ((unsigned)h1l << 16);
      if (LAYER == 1 && t == TT-1) fcp = hv[0]*wfcv[0] + hv[1]*wfcv[1];
    }

    // ---- back-pressure validation (prefetched; gates ring write via B3) ----
    if (needbp){
      asm volatile("s_waitcnt vmcnt(0)" ::: "memory");
      asm volatile("" : "+v"(bpv));
      int v = bpv;
      v = min(v, __shfl_xor(v, 1, 64));
      v = min(v, __shfl_xor(v, 2, 64));
      v = min(v, __shfl_xor(v, 4, 64));
      v = min(v, __shfl_xor(v, 8, 64));
      if (v < t-RD+1) v = poll_prog(progp, lane, t-RD+1, v);
      kn_bp = v;
    }
    __syncthreads();                           // B3: hbuf ready + bp cleared

    // ---- ring write: ONE aligned 16B store per thread {p0,seq,p1,seq} ----
    {
      const unsigned* hb32 = (const unsigned*)hbuf;
      const unsigned sq = (unsigned)(t+1);
      v4u u; u.x = hb32[2*tid]; u.y = sq; u.z = hb32[2*tid+1]; u.w = sq;
      char* dst = ringwb + (size_t)(t&(RD-1))*SLOT_SZ + (size_t)bg*65536
                + (size_t)sl*4096 + (size_t)tid*16;
      st_u16(dst, u);
    }
  }

  // ---- FC epilogue ----
  if (LAYER == 1){
    __syncthreads();
    gatesL[tid] = fcp;
    __syncthreads();
    if (tid < 32){
      float sm = 0.f;
      #pragma unroll
      for (int q = 0; q < 8; ++q) sm += gatesL[q*32 + tid];
      if (sl == 0) sm += bfc[0];
      atomicAdd(&out[bg*32 + tid], sm);
    }
  }
}

__global__ __launch_bounds__(256,1) void lstm_pipe(const float* __restrict__ x, char* __restrict__ ws,
                                                   const float* __restrict__ Wfc, const float* __restrict__ bfc,
                                                   float* __restrict__ out){
  __shared__ __align__(16) short Afr[32768];          // 65,536 B
  __shared__ __align__(16) float gatesL[2176];        //  8,704 B
  __shared__ __align__(16) float cst[544];            //  2,176 B
  __shared__ __align__(16) unsigned short hbuf[1024]; //  2,048 B
  const int bid = blockIdx.x;
  // bid&7 = bg (XCD round-robin friendly; correctness mapping-independent)
  const int bg = bid & 7, r = bid >> 3, layer = r >> 4, sl = r & 15;
  if (layer == 0) run_layer<0>(x, ws, Wfc, bfc, out, bg, sl, Afr, gatesL, cst, hbuf);
  else            run_layer<1>(x, ws, Wfc, bfc, out, bg, sl, Afr, gatesL, cst, hbuf);
}

extern "C" void kernel_launch(void* const* d_in, const int* in_sizes, int n_in,
                              void* d_out, int out_size, void* d_ws, size_t ws_size,
                              hipStream_t stream) {
  const float* x    = (const float*)d_in[0];
  const float* Wih0 = (const float*)d_in[1];
  const float* Whh0 = (const float*)d_in[2];
  const float* bih0 = (const float*)d_in[3];
  const float* bhh0 = (const float*)d_in[4];
  const float* Wih1 = (const float*)d_in[5];
  const float* Whh1 = (const float*)d_in[6];
  const float* bih1 = (const float*)d_in[7];
  const float* bhh1 = (const float*)d_in[8];
  const float* Wfc  = (const float*)d_in[9];
  const float* bfc  = (const float*)d_in[10];
  float* out = (float*)d_out;
  char* ws   = (char*)d_ws;
  (void)in_sizes; (void)n_in; (void)out_size; (void)ws_size;

  // pack items: 589824+1048576+2048+2097152+256+128 = 3,737,984 -> 14602 blocks
  pack_all<<<14602, 256, 0, stream>>>(Wih0, Whh0, bih0, bhh0, Wih1, Whh1, bih1, bhh1, ws, out);
  lstm_pipe<<<256, 256, 0, stream>>>(x, ws, Wfc, bfc, out);
}